// Round 1
// baseline (1378.160 us; speedup 1.0000x reference)
//
#include <hip/hip_runtime.h>

typedef unsigned int u32;
typedef unsigned short u16;
typedef _Float16 h2_t __attribute__((ext_vector_type(2)));

constexpr int TT = 512;   // timesteps
constexpr int FF = 64;    // input features
constexpr int H1 = 128;   // layer-1 hidden
constexpr int G1 = 4 * H1; // 512 gate cols
constexpr int H2 = 64;    // layer-2 hidden
constexpr int G2 = 4 * H2; // 256 gate cols
constexpr int D1 = 25;    // dense-1 width

__device__ __forceinline__ float fdot2(u32 a, u32 b, float c) {
#if __has_builtin(__builtin_amdgcn_fdot2)
    return __builtin_amdgcn_fdot2(__builtin_bit_cast(h2_t, a),
                                  __builtin_bit_cast(h2_t, b), c, false);
#else
    h2_t ha = __builtin_bit_cast(h2_t, a), hb = __builtin_bit_cast(h2_t, b);
    return c + (float)ha[0] * (float)hb[0] + (float)ha[1] * (float)hb[1];
#endif
}

__device__ __forceinline__ u16 f16b(float v) {
    _Float16 h = (_Float16)v;
    return __builtin_bit_cast(u16, h);
}
__device__ __forceinline__ u32 packh(float a, float b) {
    h2_t h; h[0] = (_Float16)a; h[1] = (_Float16)b;
    return __builtin_bit_cast(u32, h);
}
__device__ __forceinline__ float sigm(float z) { return 1.f / (1.f + expf(-z)); }

// One block = 2 batch rows, full T loop for both LSTM layers + dense head.
// Weights register-stationary per thread-column (fp16 pairs), h via LDS
// broadcast, v_dot2_f32_f16 MACs, fp32 accumulators and gate math.
__global__ __launch_bounds__(512, 2)
void lstm_fused(const float* __restrict__ x,  const float* __restrict__ W1,
                const float* __restrict__ U1, const float* __restrict__ b1,
                const float* __restrict__ W2, const float* __restrict__ U2,
                const float* __restrict__ b2, const float* __restrict__ Wd1,
                const float* __restrict__ bd1,const float* __restrict__ Wd2,
                const float* __restrict__ bd2,
                float* __restrict__ out, u16* __restrict__ h1seq)
{
    const int j  = threadIdx.x;          // 0..511
    const int b0 = blockIdx.x * 2;       // 2 batch rows per block

    __shared__ __align__(16) u32  x_shp[2][FF / 2];   // x[t] fp16 pairs
    __shared__ __align__(16) u32  h_shp[2][H1 / 2];   // h1 fp16 pairs
    __shared__ float z_sh[2][G1];
    __shared__ __align__(16) u32  a_shp[2][H1 / 2];   // phase-2 input pairs
    __shared__ __align__(16) u32  h2_shp[2][H2 / 2];  // h2 fp16 pairs
    __shared__ float z2_sh[2][G2];
    __shared__ float h2f_sh[2][H2];
    __shared__ float d_sh[2][D1];

    // ------------------- phase 1: layer-1 LSTM -------------------
    u32 w1c[FF / 2];   // W1[:, j] packed fp16 pairs  (32 regs)
    u32 u1c[H1 / 2];   // U1[:, j] packed fp16 pairs  (64 regs)
#pragma unroll
    for (int f2 = 0; f2 < FF / 2; ++f2)
        w1c[f2] = packh(W1[(2 * f2) * G1 + j], W1[(2 * f2 + 1) * G1 + j]);
#pragma unroll
    for (int k2 = 0; k2 < H1 / 2; ++k2)
        u1c[k2] = packh(U1[(2 * k2) * G1 + j], U1[(2 * k2 + 1) * G1 + j]);
    const float bias1 = b1[j];
    float c1 = 0.f;   // cell state owned by gate thread (j<256)

    if (j < 128) (&h_shp[0][0])[j] = 0u;            // h1 = 0
    if (j >= 384) {                                  // stage x[t=0]
        int i = j - 384, b = i >> 6, f = i & 63;
        ((u16*)&x_shp[0][0])[b * FF + f] = f16b(x[(size_t)(b0 + b) * TT * FF + f]);
    }
    __syncthreads();

    for (int t = 0; t < TT; ++t) {
        float a0 = bias1, a1 = bias1, a2 = 0.f, a3 = 0.f;
        const uint4* xp0 = (const uint4*)(&x_shp[0][0]);
        const uint4* xp1 = (const uint4*)(&x_shp[1][0]);
#pragma unroll
        for (int q = 0; q < FF / 8; ++q) {           // x @ W1 part
            uint4 xv0 = xp0[q], xv1 = xp1[q];
            a0 = fdot2(xv0.x, w1c[4 * q + 0], a0);  a1 = fdot2(xv1.x, w1c[4 * q + 0], a1);
            a2 = fdot2(xv0.y, w1c[4 * q + 1], a2);  a3 = fdot2(xv1.y, w1c[4 * q + 1], a3);
            a0 = fdot2(xv0.z, w1c[4 * q + 2], a0);  a1 = fdot2(xv1.z, w1c[4 * q + 2], a1);
            a0 = fdot2(xv0.w, w1c[4 * q + 3], a0);  a1 = fdot2(xv1.w, w1c[4 * q + 3], a1);
        }
        const uint4* hp0 = (const uint4*)(&h_shp[0][0]);
        const uint4* hp1 = (const uint4*)(&h_shp[1][0]);
#pragma unroll
        for (int q = 0; q < H1 / 8; ++q) {           // h @ U1 part
            uint4 hv0 = hp0[q], hv1 = hp1[q];
            a0 = fdot2(hv0.x, u1c[4 * q + 0], a0);  a1 = fdot2(hv1.x, u1c[4 * q + 0], a1);
            a2 = fdot2(hv0.y, u1c[4 * q + 1], a2);  a3 = fdot2(hv1.y, u1c[4 * q + 1], a3);
            a0 = fdot2(hv0.z, u1c[4 * q + 2], a0);  a1 = fdot2(hv1.z, u1c[4 * q + 2], a1);
            a2 = fdot2(hv0.w, u1c[4 * q + 3], a2);  a3 = fdot2(hv1.w, u1c[4 * q + 3], a3);
        }
        z_sh[0][j] = a0 + a2;
        z_sh[1][j] = a1 + a3;
        __syncthreads();

        if (j < 256) {                               // gate update (b,k)
            int b = j >> 7, k = j & 127;
            float zi = z_sh[b][k],        zf = z_sh[b][128 + k];
            float zg = z_sh[b][256 + k],  zo = z_sh[b][384 + k];
            float ig = sigm(zi), fg = sigm(zf), gg = fmaxf(zg, 0.f), og = sigm(zo);
            c1 = fg * c1 + ig * gg;
            float h = og * fmaxf(c1, 0.f);
            u16 hb = f16b(h);
            ((u16*)&h_shp[0][0])[b * H1 + k] = hb;
            h1seq[((size_t)(b0 + b) * TT + t) * H1 + k] = hb;
        } else if (j >= 384) {                       // stage x[t+1]
            if (t + 1 < TT) {
                int i = j - 384, b = i >> 6, f = i & 63;
                ((u16*)&x_shp[0][0])[b * FF + f] =
                    f16b(x[(size_t)(b0 + b) * TT * FF + (size_t)(t + 1) * FF + f]);
            }
        }
        __syncthreads();
    }

    __threadfence_block();   // make h1seq global writes visible in-block
    __syncthreads();

    // ------------------- phase 2: layer-2 LSTM -------------------
    u32 w2c[H1 / 2];   // W2[:, j] pairs (64 regs), only j<256 valid
    u32 u2c[H2 / 2];   // U2[:, j] pairs (32 regs)
    float bias2 = 0.f, c2 = 0.f;
    if (j < 256) {
#pragma unroll
        for (int k2 = 0; k2 < H1 / 2; ++k2)
            w2c[k2] = packh(W2[(2 * k2) * G2 + j], W2[(2 * k2 + 1) * G2 + j]);
#pragma unroll
        for (int k2 = 0; k2 < H2 / 2; ++k2)
            u2c[k2] = packh(U2[(2 * k2) * G2 + j], U2[(2 * k2 + 1) * G2 + j]);
        bias2 = b2[j];
    }
    if (j < 64) (&h2_shp[0][0])[j] = 0u;             // h2 = 0
    if (j < 128) {                                   // stage h1seq[t=0]
        int b = j >> 6, f2 = j & 63;
        a_shp[b][f2] = ((const u32*)h1seq)[((size_t)(b0 + b) * TT) * (H1 / 2) + f2];
    }
    __syncthreads();

    for (int t = 0; t < TT; ++t) {
        if (j < 256) {
            float a0 = bias2, a1 = bias2, a2 = 0.f, a3 = 0.f;
            const uint4* ap0 = (const uint4*)(&a_shp[0][0]);
            const uint4* ap1 = (const uint4*)(&a_shp[1][0]);
#pragma unroll
            for (int q = 0; q < H1 / 8; ++q) {       // h1 @ W2 part
                uint4 av0 = ap0[q], av1 = ap1[q];
                a0 = fdot2(av0.x, w2c[4 * q + 0], a0);  a1 = fdot2(av1.x, w2c[4 * q + 0], a1);
                a2 = fdot2(av0.y, w2c[4 * q + 1], a2);  a3 = fdot2(av1.y, w2c[4 * q + 1], a3);
                a0 = fdot2(av0.z, w2c[4 * q + 2], a0);  a1 = fdot2(av1.z, w2c[4 * q + 2], a1);
                a2 = fdot2(av0.w, w2c[4 * q + 3], a2);  a3 = fdot2(av1.w, w2c[4 * q + 3], a3);
            }
            const uint4* hp0 = (const uint4*)(&h2_shp[0][0]);
            const uint4* hp1 = (const uint4*)(&h2_shp[1][0]);
#pragma unroll
            for (int q = 0; q < H2 / 8; ++q) {       // h2 @ U2 part
                uint4 hv0 = hp0[q], hv1 = hp1[q];
                a0 = fdot2(hv0.x, u2c[4 * q + 0], a0);  a1 = fdot2(hv1.x, u2c[4 * q + 0], a1);
                a2 = fdot2(hv0.y, u2c[4 * q + 1], a2);  a3 = fdot2(hv1.y, u2c[4 * q + 1], a3);
                a0 = fdot2(hv0.z, u2c[4 * q + 2], a0);  a1 = fdot2(hv1.z, u2c[4 * q + 2], a1);
                a2 = fdot2(hv0.w, u2c[4 * q + 3], a2);  a3 = fdot2(hv1.w, u2c[4 * q + 3], a3);
            }
            z2_sh[0][j] = a0 + a2;
            z2_sh[1][j] = a1 + a3;
        }
        __syncthreads();

        if (j < 128) {                               // gate update (b,k)
            int b = j >> 6, k = j & 63;
            float zi = z2_sh[b][k],        zf = z2_sh[b][64 + k];
            float zg = z2_sh[b][128 + k],  zo = z2_sh[b][192 + k];
            float ig = sigm(zi), fg = sigm(zf), gg = fmaxf(zg, 0.f), og = sigm(zo);
            c2 = fg * c2 + ig * gg;
            float h = og * fmaxf(c2, 0.f);
            ((u16*)&h2_shp[0][0])[b * H2 + k] = f16b(h);
            h2f_sh[b][k] = h;
        } else if (j < 256) {                        // stage h1seq[t+1]
            if (t + 1 < TT) {
                int i = j - 128, b = i >> 6, f2 = i & 63;
                a_shp[b][f2] =
                    ((const u32*)h1seq)[((size_t)(b0 + b) * TT + (t + 1)) * (H1 / 2) + f2];
            }
        }
        __syncthreads();
    }

    // ------------------- dense head -------------------
    if (j < 2 * D1) {
        int b = j / D1, p = j % D1;
        float d = bd1[p];
#pragma unroll
        for (int k = 0; k < H2; ++k) d += h2f_sh[b][k] * Wd1[k * D1 + p];
        d_sh[b][p] = d * Wd2[p];
    }
    __syncthreads();
    if (j < 2) {
        float o = bd2[0];
#pragma unroll
        for (int p = 0; p < D1; ++p) o += d_sh[j][p];
        out[b0 + j] = o;
    }
}

extern "C" void kernel_launch(void* const* d_in, const int* in_sizes, int n_in,
                              void* d_out, int out_size, void* d_ws, size_t ws_size,
                              hipStream_t stream) {
    (void)in_sizes; (void)n_in; (void)out_size; (void)ws_size;
    const float* x   = (const float*)d_in[0];
    const float* W1  = (const float*)d_in[1];
    const float* U1  = (const float*)d_in[2];
    const float* b1  = (const float*)d_in[3];
    const float* W2  = (const float*)d_in[4];
    const float* U2  = (const float*)d_in[5];
    const float* b2  = (const float*)d_in[6];
    const float* Wd1 = (const float*)d_in[7];
    const float* bd1 = (const float*)d_in[8];
    const float* Wd2 = (const float*)d_in[9];
    const float* bd2 = (const float*)d_in[10];
    float* out   = (float*)d_out;
    u16*   h1seq = (u16*)d_ws;   // needs 512*512*128*2 = 64 MiB scratch

    lstm_fused<<<dim3(256), dim3(512), 0, stream>>>(
        x, W1, U1, b1, W2, U2, b2, Wd1, bd1, Wd2, bd2, out, h1seq);
}